// Round 1
// baseline (653.282 us; speedup 1.0000x reference)
//
#include <hip/hip_runtime.h>
#include <hip/hip_fp16.h>
#include <math.h>

// ReactiveChristoffel fused implementation for MI355X (gfx950).
// K0: gate_w/forget_w fp32 -> fp16 into ws ([2048][1024], rows 0-1023 gate, 1024-2047 forget)
// K1: per-row stats: sq[row][16] = proj^2/(1+||proj||), pot[row], mult[row]
// K2: dual-B fp16 MFMA GEMM (gate+forget logits) with fully fused epilogue.

#define NROWS 32768
#define DIMD  1024

typedef float    f32x4 __attribute__((ext_vector_type(4)));
typedef _Float16 f16x8 __attribute__((ext_vector_type(8)));
typedef _Float16 f16x4 __attribute__((ext_vector_type(4)));

// ---------------- K0: weight conversion ----------------
__global__ __launch_bounds__(256)
void k0_convert_w(const float* __restrict__ gw, const float* __restrict__ fw,
                  __half* __restrict__ wh) {
    const int NG = (2 * 1024 * 1024) / 4;
    for (int g = blockIdx.x * blockDim.x + threadIdx.x; g < NG; g += gridDim.x * blockDim.x) {
        int idx = g * 4;
        const float* src = (idx < 1024 * 1024) ? (gw + idx) : (fw + (idx - 1024 * 1024));
        f32x4 s = *(const f32x4*)src;
        f16x4 h;
        h[0] = (_Float16)s[0]; h[1] = (_Float16)s[1];
        h[2] = (_Float16)s[2]; h[3] = (_Float16)s[3];
        *(f16x4*)(wh + idx) = h;
    }
}

// ---------------- K1: per-row statistics ----------------
__global__ __launch_bounds__(256)
void k1_rowstats(const float* __restrict__ v, const float* __restrict__ x,
                 const float* __restrict__ U, const float* __restrict__ Vw,
                 float* __restrict__ sq_o, float* __restrict__ pot_o,
                 float* __restrict__ mult_o) {
    __shared__ float Us[1024][20];   // +4 pad: stride 80B -> conflict-free b128 reads
    __shared__ float Vws[1024];
    const int tid = threadIdx.x;
    #pragma unroll
    for (int c = 0; c < 4; ++c) {
        int d = tid + 256 * c;
        const float* ur = U + (size_t)d * 16;
        *(f32x4*)&Us[d][0]  = *(const f32x4*)(ur);
        *(f32x4*)&Us[d][4]  = *(const f32x4*)(ur + 4);
        *(f32x4*)&Us[d][8]  = *(const f32x4*)(ur + 8);
        *(f32x4*)&Us[d][12] = *(const f32x4*)(ur + 12);
        Vws[d] = Vw[d];
    }
    __syncthreads();
    const int lane = tid & 63, wave = tid >> 6;
    const int gwv = blockIdx.x * 4 + wave;           // 0..4095, wave-per-row
    for (int rr = 0; rr < 8; ++rr) {
        int row = gwv + rr * 4096;
        const float* vr = v + (size_t)row * DIMD;
        const float* xr = x + (size_t)row * DIMD;
        float en = 0.f, pt = 0.f;
        float pr[16];
        #pragma unroll
        for (int r = 0; r < 16; ++r) pr[r] = 0.f;
        #pragma unroll 4
        for (int c = 0; c < 16; ++c) {
            int d = lane + 64 * c;
            float vv = vr[d];
            float xx = xr[d];
            en = fmaf(vv, vv, en);
            pt = fmaf(xx, Vws[d], pt);
            const float* up = &Us[d][0];
            #pragma unroll
            for (int r = 0; r < 16; ++r) pr[r] = fmaf(vv, up[r], pr[r]);
        }
        #pragma unroll
        for (int off = 32; off >= 1; off >>= 1) {
            en += __shfl_xor(en, off, 64);
            pt += __shfl_xor(pt, off, 64);
            #pragma unroll
            for (int r = 0; r < 16; ++r) pr[r] += __shfl_xor(pr[r], off, 64);
        }
        if (lane == 0) {
            float n2 = 0.f;
            #pragma unroll
            for (int r = 0; r < 16; ++r) n2 = fmaf(pr[r], pr[r], n2);
            float scale = 1.f / (1.f + sqrtf(n2));
            float p = 1.f / (1.f + expf(-pt));           // fp32-exact potential
            float energy = tanhf(en * (1.f / 1024.f));
            float mu = (1.f + 0.5f * energy) * (p > 0.8f ? 10.f : 1.f);
            float* sqr = sq_o + (size_t)row * 16;
            #pragma unroll
            for (int r = 0; r < 16; ++r) sqr[r] = pr[r] * pr[r] * scale;
            pot_o[row] = p;
            mult_o[row] = mu;
        }
    }
}

// ---------------- K2: fused dual GEMM + epilogue ----------------
// BM=128 rows, BN=64 cols (x2 matrices), BK=64, 256 threads (4 waves, 2x2).
__global__ __launch_bounds__(256)
void k2_main(const float* __restrict__ x, const float* __restrict__ v,
             const __half* __restrict__ wh,
             const float* __restrict__ W, const float* __restrict__ gate_b,
             const float* __restrict__ forget_b, const float* __restrict__ sq_i,
             const float* __restrict__ pot_i, const float* __restrict__ mult_i,
             float* __restrict__ out) {
    __shared__ __half As[128][72];      // +8 pad -> 144B stride, conflict-free frag reads
    __shared__ __half Bs[2][64][64];    // linear (global_load_lds dest), XOR-swizzled content
    __shared__ float  sqs[128][16];
    __shared__ float  Ws[64][20];
    __shared__ float  pots[128];
    __shared__ float  mults[128];
    __shared__ float  gbs[64];
    __shared__ float  fbs[64];

    const int tid  = threadIdx.x;
    const int lane = tid & 63, wave = tid >> 6;
    const int nt = blockIdx.x, mt = blockIdx.y;     // nt fastest: 16 blocks share one x stripe
    const int m0 = mt * 128, n0 = nt * 64;
    const int wm = (wave >> 1) * 64, wn = (wave & 1) * 32;

    // ---- stage epilogue data ----
    {
        int r = tid >> 1, h = tid & 1;
        const float* s = sq_i + (size_t)(m0 + r) * 16 + h * 8;
        *(f32x4*)&sqs[r][h * 8]     = *(const f32x4*)(s);
        *(f32x4*)&sqs[r][h * 8 + 4] = *(const f32x4*)(s + 4);
        if (tid < 128) { pots[tid] = pot_i[m0 + tid]; mults[tid] = mult_i[m0 + tid]; }
        if (tid < 64)  { gbs[tid] = gate_b[n0 + tid]; fbs[tid] = forget_b[n0 + tid]; }
        int wr_ = tid >> 2, wq = tid & 3;
        *(f32x4*)&Ws[wr_][wq * 4] = *(const f32x4*)(W + (size_t)(n0 + wr_) * 16 + wq * 4);
    }

    f32x4 acc[2][4][2];
    #pragma unroll
    for (int a = 0; a < 2; ++a)
        #pragma unroll
        for (int m = 0; m < 4; ++m)
            #pragma unroll
            for (int n = 0; n < 2; ++n)
                acc[a][m][n] = (f32x4){0.f, 0.f, 0.f, 0.f};

    // B source lane mapping for global_load_lds (1KB chunk = 8 rows x 64B):
    const int bn = lane >> 3;              // row within chunk (== n & 7)
    const int bs = (lane & 7) ^ bn;        // pre-swizzled k-slot (16B units)
    const int mat = wave >> 1;             // waves 0-1: gate, waves 2-3: forget
    const __half* wsrc = wh + (size_t)(mat * 1024 + n0) * 1024;

    const int ar = tid >> 4;               // A staging: row base 0..15
    const int ac = tid & 15;               // col quad
    const float* xbase = x + (size_t)(m0 + ar) * 1024 + ac * 4;

    for (int kt = 0; kt < 16; ++kt) {
        // B: each wave issues 4 x 1KB direct-to-LDS chunks
        #pragma unroll
        for (int cc = 0; cc < 4; ++cc) {
            int c = (wave & 1) * 4 + cc;
            const __half* g = wsrc + (size_t)(c * 8 + bn) * 1024 + kt * 64 + bs * 8;
            __builtin_amdgcn_global_load_lds(
                (const __attribute__((address_space(1))) void*)g,
                (__attribute__((address_space(3))) void*)&Bs[mat][c * 8][0],
                16, 0, 0);
        }
        // A: reg-stage fp32 -> fp16 into padded LDS
        const float* xk = xbase + kt * 64;
        f32x4 xa[8];
        #pragma unroll
        for (int p = 0; p < 8; ++p) xa[p] = *(const f32x4*)(xk + (size_t)p * 16 * 1024);
        #pragma unroll
        for (int p = 0; p < 8; ++p) {
            f16x4 h;
            h[0] = (_Float16)xa[p][0]; h[1] = (_Float16)xa[p][1];
            h[2] = (_Float16)xa[p][2]; h[3] = (_Float16)xa[p][3];
            *(f16x4*)&As[p * 16 + ar][ac * 4] = h;
        }
        __syncthreads();

        #pragma unroll
        for (int kk = 0; kk < 2; ++kk) {
            f16x8 af[4];
            #pragma unroll
            for (int m = 0; m < 4; ++m) {
                int row = wm + m * 16 + (lane & 15);
                af[m] = *(const f16x8*)((const __half*)&As[row][0] + (lane >> 4) * 8 + kk * 32);
            }
            f16x8 bf[2][2];
            #pragma unroll
            for (int n = 0; n < 2; ++n) {
                int brow = wn + n * 16 + (lane & 15);
                int slot = ((lane >> 4) + kk * 4) ^ (brow & 7);
                bf[0][n] = *(const f16x8*)&Bs[0][brow][slot * 8];
                bf[1][n] = *(const f16x8*)&Bs[1][brow][slot * 8];
            }
            #pragma unroll
            for (int m = 0; m < 4; ++m)
                #pragma unroll
                for (int n = 0; n < 2; ++n) {
                    acc[0][m][n] = __builtin_amdgcn_mfma_f32_16x16x32_f16(af[m], bf[0][n], acc[0][m][n], 0, 0, 0);
                    acc[1][m][n] = __builtin_amdgcn_mfma_f32_16x16x32_f16(af[m], bf[1][n], acc[1][m][n], 0, 0, 0);
                }
        }
        __syncthreads();
    }

    // ---- epilogue ----
    const int cl = lane & 15;
    const int rq = lane >> 4;
    float gb2[2], fb2[2];
    f32x4 Wf[2][4];
    #pragma unroll
    for (int n = 0; n < 2; ++n) {
        int c = wn + n * 16 + cl;
        #pragma unroll
        for (int q = 0; q < 4; ++q) Wf[n][q] = *(const f32x4*)&Ws[c][q * 4];
        gb2[n] = gbs[c]; fb2[n] = fbs[c];
    }
    #pragma unroll
    for (int m = 0; m < 4; ++m) {
        #pragma unroll
        for (int i = 0; i < 4; ++i) {
            int rl = wm + m * 16 + rq * 4 + i;
            size_t gm = (size_t)(m0 + rl);
            f32x4 sr[4];
            #pragma unroll
            for (int q = 0; q < 4; ++q) sr[q] = *(const f32x4*)&sqs[rl][q * 4];
            float ptl = pots[rl], mu = mults[rl];
            float onep = 1.f + ptl;
            #pragma unroll
            for (int n = 0; n < 2; ++n) {
                float gamma = 0.f;
                #pragma unroll
                for (int q = 0; q < 4; ++q)
                    #pragma unroll
                    for (int j = 0; j < 4; ++j)
                        gamma = fmaf(sr[q][j], Wf[n][q][j], gamma);
                int gn = n0 + wn + n * 16 + cl;
                float gl = acc[0][m][n][i] + gb2[n];
                float fl = acc[1][m][n][i] + fb2[n];
                float gate = 1.f / (1.f + __expf(-gl));
                float fric = 1.f / (1.f + __expf(-fl));
                float gam = gamma * onep;
                gam = fminf(fmaxf(gam, -5.f), 5.f) * gate;
                float vv = v[gm * 1024 + gn];
                out[gm * 1024 + gn] = (gam + fric * vv) * mu;
            }
        }
    }
}

extern "C" void kernel_launch(void* const* d_in, const int* in_sizes, int n_in,
                              void* d_out, int out_size, void* d_ws, size_t ws_size,
                              hipStream_t stream) {
    const float* v  = (const float*)d_in[0];
    const float* x  = (const float*)d_in[1];
    const float* U  = (const float*)d_in[2];
    const float* W  = (const float*)d_in[3];
    const float* Vw = (const float*)d_in[4];
    const float* gw = (const float*)d_in[5];
    const float* gb = (const float*)d_in[6];
    const float* fw = (const float*)d_in[7];
    const float* fb = (const float*)d_in[8];
    float* out = (float*)d_out;

    // ws layout: [0,4MB) fp16 weights; [4MB,6MB) sq; then pot, mult. ~6.4 MB total.
    __half* wh  = (__half*)d_ws;
    float* sq   = (float*)((char*)d_ws + (size_t)4 * 1024 * 1024);
    float* pot  = (float*)((char*)d_ws + (size_t)6 * 1024 * 1024);
    float* mult = (float*)((char*)d_ws + (size_t)6 * 1024 * 1024 + 131072);

    hipLaunchKernelGGL(k0_convert_w, dim3(1024), dim3(256), 0, stream, gw, fw, wh);
    hipLaunchKernelGGL(k1_rowstats,  dim3(1024), dim3(256), 0, stream, v, x, U, Vw, sq, pot, mult);
    hipLaunchKernelGGL(k2_main, dim3(16, 256), dim3(256), 0, stream,
                       x, v, wh, W, gb, fb, sq, pot, mult, out);
}

// Round 3
// 591.014 us; speedup vs baseline: 1.1054x; 1.1054x over previous
//
#include <hip/hip_runtime.h>
#include <hip/hip_fp16.h>
#include <math.h>

typedef float    f32x4 __attribute__((ext_vector_type(4)));
typedef _Float16 f16x8 __attribute__((ext_vector_type(8)));
typedef _Float16 f16x4 __attribute__((ext_vector_type(4)));

#define AS1 __attribute__((address_space(1)))
#define AS3 __attribute__((address_space(3)))

// ws layout:
//   [0, 4MB)            wh   : fp16 weights [2][1024][1024] (gate, forget), row-major [e][d]
//   [4MB, 4MB+64KB)     uht  : fp16 U^T [16][1032] (pad 1032 for 16B-aligned rows)
//   [4MB+64KB, +2MB)    sq   : f32 [32768][16]
//   then                pot  : f32 [32768]
//   then                mult : f32 [32768]
//   [8MB, 8MB+64MB)     xh   : fp16 x tiled [256 mt][16 kt][128 row][64], phys slot = slot^(row&7)

// ---------------- k0w: weights + U^T conversion ----------------
__global__ __launch_bounds__(256)
void k0_convert(const float* __restrict__ gw, const float* __restrict__ fw,
                const float* __restrict__ U, _Float16* __restrict__ wh,
                _Float16* __restrict__ uht) {
    const int NG = (2 * 1024 * 1024) / 4;
    for (int g = blockIdx.x * 256 + threadIdx.x; g < NG; g += gridDim.x * 256) {
        int idx = g * 4;
        const float* src = (idx < 1024 * 1024) ? (gw + idx) : (fw + (idx - 1024 * 1024));
        f32x4 s = *(const f32x4*)src;
        f16x4 h;
        h[0] = (_Float16)s[0]; h[1] = (_Float16)s[1];
        h[2] = (_Float16)s[2]; h[3] = (_Float16)s[3];
        *(f16x4*)(wh + idx) = h;
    }
    if (blockIdx.x < 64) {
        int g = blockIdx.x * 256 + threadIdx.x;   // 0..16383
        int k = g >> 4, r = g & 15;
        uht[r * 1032 + k] = (_Float16)U[k * 16 + r];
    }
}

// ---------------- k0x: x -> fp16 tiled/swizzled + potential dot (fp32) ----------------
template<bool WRITE_XH>
__global__ __launch_bounds__(256)
void k0_x(const float* __restrict__ x, const float* __restrict__ Vw,
          _Float16* __restrict__ xh, float* __restrict__ pot_o) {
    __shared__ float Vws[1024];
    const int tid = threadIdx.x;
    #pragma unroll
    for (int c = 0; c < 4; ++c) Vws[tid + 256 * c] = Vw[tid + 256 * c];
    __syncthreads();
    const int mt = blockIdx.x, m0 = mt * 128;
    const int row = tid >> 1, half = tid & 1;
    const float* xr = x + (size_t)(m0 + row) * 1024 + half * 32;
    _Float16* xtile = xh + (size_t)mt * 16 * 128 * 64;
    float pt = 0.f;
    for (int kt = 0; kt < 16; ++kt) {
        f32x4 a[8];
        #pragma unroll
        for (int j = 0; j < 8; ++j) a[j] = *(const f32x4*)(xr + kt * 64 + j * 4);
        #pragma unroll
        for (int j = 0; j < 8; ++j) {
            const float* vw = &Vws[kt * 64 + half * 32 + j * 4];
            pt = fmaf(a[j][0], vw[0], pt); pt = fmaf(a[j][1], vw[1], pt);
            pt = fmaf(a[j][2], vw[2], pt); pt = fmaf(a[j][3], vw[3], pt);
        }
        if (WRITE_XH) {
            _Float16* rowp = xtile + ((size_t)kt * 128 + row) * 64;
            #pragma unroll
            for (int jj = 0; jj < 4; ++jj) {
                int slot = half * 4 + jj;
                int phys = slot ^ (row & 7);
                f16x8 h;
                h[0] = (_Float16)a[2*jj][0];   h[1] = (_Float16)a[2*jj][1];
                h[2] = (_Float16)a[2*jj][2];   h[3] = (_Float16)a[2*jj][3];
                h[4] = (_Float16)a[2*jj+1][0]; h[5] = (_Float16)a[2*jj+1][1];
                h[6] = (_Float16)a[2*jj+1][2]; h[7] = (_Float16)a[2*jj+1][3];
                *(f16x8*)(rowp + phys * 8) = h;
            }
        }
    }
    pt += __shfl_xor(pt, 1, 64);
    if (half == 0) pot_o[m0 + row] = 1.f / (1.f + expf(-pt));
}

// ---------------- k1v: v-stream — proj via MFMA, energy, sq, mult ----------------
// NOTE: no __syncthreads in the kt loop — each wave writes exactly the 16 LDS
// rows it reads (row=tid>>2 in [w*16,w*16+16), frow=w*16+(lane&15)); per-wave
// DS ops are in-order and the compiler inserts lgkmcnt waits on the reg dep.
__global__ __launch_bounds__(256)
void k1_v(const float* __restrict__ v, const _Float16* __restrict__ uht,
          const float* __restrict__ pot_i, float* __restrict__ sq_o,
          float* __restrict__ mult_o) {
    __shared__ _Float16 Av[64][64];    // 8 KB, XOR-swizzled slots
    const int tid = threadIdx.x, lane = tid & 63, w = tid >> 6;
    const int m0 = blockIdx.x * 64;
    const int row = tid >> 2, q = tid & 3;        // 4 threads per row, 16 cols each
    const float* vr = v + (size_t)(m0 + row) * 1024 + q * 16;
    const _Float16* bsrc = uht + (lane & 15) * 1032 + (lane >> 4) * 8;
    float en = 0.f;
    f32x4 acc = {0.f, 0.f, 0.f, 0.f};
    const int frow = w * 16 + (lane & 15);
    for (int kt = 0; kt < 16; ++kt) {
        f16x8 bf0 = *(const f16x8*)(bsrc + kt * 64);
        f16x8 bf1 = *(const f16x8*)(bsrc + kt * 64 + 32);
        f32x4 a[4];
        #pragma unroll
        for (int j = 0; j < 4; ++j) a[j] = *(const f32x4*)(vr + kt * 64 + j * 4);
        #pragma unroll
        for (int j = 0; j < 4; ++j) {
            en = fmaf(a[j][0], a[j][0], en); en = fmaf(a[j][1], a[j][1], en);
            en = fmaf(a[j][2], a[j][2], en); en = fmaf(a[j][3], a[j][3], en);
        }
        #pragma unroll
        for (int jj = 0; jj < 2; ++jj) {
            int slot = q * 2 + jj;
            int phys = slot ^ (row & 7);
            f16x8 h;
            h[0] = (_Float16)a[2*jj][0];   h[1] = (_Float16)a[2*jj][1];
            h[2] = (_Float16)a[2*jj][2];   h[3] = (_Float16)a[2*jj][3];
            h[4] = (_Float16)a[2*jj+1][0]; h[5] = (_Float16)a[2*jj+1][1];
            h[6] = (_Float16)a[2*jj+1][2]; h[7] = (_Float16)a[2*jj+1][3];
            *(f16x8*)&Av[row][phys * 8] = h;
        }
        #pragma unroll
        for (int kk = 0; kk < 2; ++kk) {
            int lg = (lane >> 4) + kk * 4;
            int phys = lg ^ (frow & 7);
            f16x8 af = *(const f16x8*)&Av[frow][phys * 8];
            acc = __builtin_amdgcn_mfma_f32_16x16x32_f16(af, kk ? bf1 : bf0, acc, 0, 0, 0);
        }
    }
    // proj: component r = lane&15, row = m0 + w*16 + (lane>>4)*4 + i
    const int r = lane & 15;
    #pragma unroll
    for (int i = 0; i < 4; ++i) {
        float p2 = acc[i] * acc[i];
        p2 += __shfl_xor(p2, 1, 64);
        p2 += __shfl_xor(p2, 2, 64);
        p2 += __shfl_xor(p2, 4, 64);
        p2 += __shfl_xor(p2, 8, 64);
        float scale = 1.f / (1.f + sqrtf(p2));
        int prow = m0 + w * 16 + (lane >> 4) * 4 + i;
        sq_o[(size_t)prow * 16 + r] = acc[i] * acc[i] * scale;
    }
    en += __shfl_xor(en, 1, 64);
    en += __shfl_xor(en, 2, 64);
    if (q == 0) {
        int prow = m0 + row;
        float e = tanhf(en * (1.f / 1024.f));
        float p = pot_i[prow];
        mult_o[prow] = (1.f + 0.5f * e) * (p > 0.8f ? 10.f : 1.f);
    }
}

// ---------------- k2: fused dual GEMM + epilogue ----------------
template<bool XH>
__global__ __launch_bounds__(256)
void k2_main(const float* __restrict__ x, const float* __restrict__ v,
             const _Float16* __restrict__ wh, const _Float16* __restrict__ xh,
             const float* __restrict__ W, const float* __restrict__ gate_b,
             const float* __restrict__ forget_b, const float* __restrict__ sq_i,
             const float* __restrict__ pot_i, const float* __restrict__ mult_i,
             float* __restrict__ out) {
    __shared__ _Float16 As[128][64];    // linear dest, XOR-swizzled content
    __shared__ _Float16 Bs[2][64][64];
    __shared__ float  sqs[128][16];
    __shared__ float  Ws[64][20];
    __shared__ float  pots[128];
    __shared__ float  mults[128];
    __shared__ float  gbs[64];
    __shared__ float  fbs[64];

    const int tid  = threadIdx.x;
    const int lane = tid & 63, wave = tid >> 6;
    const int bid = blockIdx.x;
    const int swz = (bid & 7) * 512 + (bid >> 3);   // XCD-bijective: stripe-local
    const int nt = swz & 15, mt = swz >> 4;
    const int m0 = mt * 128, n0 = nt * 64;
    const int wm = (wave >> 1) * 64, wn = (wave & 1) * 32;

    {   // epilogue staging
        int r = tid >> 1, h = tid & 1;
        const float* s = sq_i + (size_t)(m0 + r) * 16 + h * 8;
        *(f32x4*)&sqs[r][h * 8]     = *(const f32x4*)(s);
        *(f32x4*)&sqs[r][h * 8 + 4] = *(const f32x4*)(s + 4);
        if (tid < 128) { pots[tid] = pot_i[m0 + tid]; mults[tid] = mult_i[m0 + tid]; }
        if (tid < 64)  { gbs[tid] = gate_b[n0 + tid]; fbs[tid] = forget_b[n0 + tid]; }
        int wr_ = tid >> 2, wq = tid & 3;
        *(f32x4*)&Ws[wr_][wq * 4] = *(const f32x4*)(W + (size_t)(n0 + wr_) * 16 + wq * 4);
    }

    f32x4 acc[2][4][2];
    #pragma unroll
    for (int a = 0; a < 2; ++a)
        #pragma unroll
        for (int m = 0; m < 4; ++m)
            #pragma unroll
            for (int n = 0; n < 2; ++n)
                acc[a][m][n] = (f32x4){0.f, 0.f, 0.f, 0.f};

    const int bn = lane >> 3;
    const int bs = (lane & 7) ^ bn;
    const int mat = wave >> 1;
    const _Float16* wsrc = wh + (size_t)(mat * 1024 + n0) * 1024;
    const _Float16* xtile = XH ? (xh + (size_t)mt * 16 * 128 * 64) : nullptr;
    const int ar = tid >> 4, ac = tid & 15;
    const float* xbase = XH ? nullptr : (x + (size_t)(m0 + ar) * 1024 + ac * 4);

    for (int kt = 0; kt < 16; ++kt) {
        // B: 2 matrices, 16 KB total via global_load_lds (pre-swizzled source)
        #pragma unroll
        for (int cc = 0; cc < 4; ++cc) {
            int c = (wave & 1) * 4 + cc;
            const _Float16* g = wsrc + (size_t)(c * 8 + bn) * 1024 + kt * 64 + bs * 8;
            __builtin_amdgcn_global_load_lds((const AS1 void*)g,
                (AS3 void*)&Bs[mat][c * 8][0], 16, 0, 0);
        }
        if (XH) {
            // A: 16 KB linear copy from pre-tiled/pre-swizzled xh
            const _Float16* xt = xtile + ((size_t)kt * 128) * 64;
            #pragma unroll
            for (int c = 0; c < 4; ++c) {
                const _Float16* g = xt + (wave * 32 + c * 8) * 64 + lane * 8;
                __builtin_amdgcn_global_load_lds((const AS1 void*)g,
                    (AS3 void*)&As[wave * 32 + c * 8][0], 16, 0, 0);
            }
        } else {
            const float* xk = xbase + kt * 64;
            #pragma unroll
            for (int p = 0; p < 8; ++p) {
                f32x4 s = *(const f32x4*)(xk + (size_t)p * 16 * 1024);
                f16x4 h;
                h[0] = (_Float16)s[0]; h[1] = (_Float16)s[1];
                h[2] = (_Float16)s[2]; h[3] = (_Float16)s[3];
                int row = p * 16 + ar;
                int phys = (ac >> 1) ^ (row & 7);
                *(f16x4*)((_Float16*)&As[row][0] + phys * 8 + (ac & 1) * 4) = h;
            }
        }
        __syncthreads();

        #pragma unroll
        for (int kk = 0; kk < 2; ++kk) {
            f16x8 af[4];
            #pragma unroll
            for (int m = 0; m < 4; ++m) {
                int row = wm + m * 16 + (lane & 15);
                int phys = ((lane >> 4) + kk * 4) ^ (row & 7);
                af[m] = *(const f16x8*)&As[row][phys * 8];
            }
            f16x8 bf[2][2];
            #pragma unroll
            for (int n = 0; n < 2; ++n) {
                int brow = wn + n * 16 + (lane & 15);
                int slot = ((lane >> 4) + kk * 4) ^ (brow & 7);
                bf[0][n] = *(const f16x8*)&Bs[0][brow][slot * 8];
                bf[1][n] = *(const f16x8*)&Bs[1][brow][slot * 8];
            }
            #pragma unroll
            for (int m = 0; m < 4; ++m)
                #pragma unroll
                for (int n = 0; n < 2; ++n) {
                    acc[0][m][n] = __builtin_amdgcn_mfma_f32_16x16x32_f16(af[m], bf[0][n], acc[0][m][n], 0, 0, 0);
                    acc[1][m][n] = __builtin_amdgcn_mfma_f32_16x16x32_f16(af[m], bf[1][n], acc[1][m][n], 0, 0, 0);
                }
        }
        __syncthreads();
    }

    // epilogue
    const int cl = lane & 15, rq = lane >> 4;
    float gb2[2], fb2[2];
    f32x4 Wf[2][4];
    #pragma unroll
    for (int n = 0; n < 2; ++n) {
        int c = wn + n * 16 + cl;
        #pragma unroll
        for (int qq = 0; qq < 4; ++qq) Wf[n][qq] = *(const f32x4*)&Ws[c][qq * 4];
        gb2[n] = gbs[c]; fb2[n] = fbs[c];
    }
    #pragma unroll
    for (int m = 0; m < 4; ++m) {
        #pragma unroll
        for (int i = 0; i < 4; ++i) {
            int rl = wm + m * 16 + rq * 4 + i;
            size_t gm = (size_t)(m0 + rl);
            f32x4 sr[4];
            #pragma unroll
            for (int qq = 0; qq < 4; ++qq) sr[qq] = *(const f32x4*)&sqs[rl][qq * 4];
            float onep = 1.f + pots[rl], mu = mults[rl];
            #pragma unroll
            for (int n = 0; n < 2; ++n) {
                float gamma = 0.f;
                #pragma unroll
                for (int qq = 0; qq < 4; ++qq)
                    #pragma unroll
                    for (int j = 0; j < 4; ++j)
                        gamma = fmaf(sr[qq][j], Wf[n][qq][j], gamma);
                int gn = n0 + wn + n * 16 + cl;
                float gl = acc[0][m][n][i] + gb2[n];
                float fl = acc[1][m][n][i] + fb2[n];
                float gate = 1.f / (1.f + __expf(-gl));
                float fric = 1.f / (1.f + __expf(-fl));
                float gam = gamma * onep;
                gam = fminf(fmaxf(gam, -5.f), 5.f) * gate;
                float vv = v[gm * 1024 + gn];
                out[gm * 1024 + gn] = (gam + fric * vv) * mu;
            }
        }
    }
}

extern "C" void kernel_launch(void* const* d_in, const int* in_sizes, int n_in,
                              void* d_out, int out_size, void* d_ws, size_t ws_size,
                              hipStream_t stream) {
    const float* v  = (const float*)d_in[0];
    const float* x  = (const float*)d_in[1];
    const float* U  = (const float*)d_in[2];
    const float* W  = (const float*)d_in[3];
    const float* Vw = (const float*)d_in[4];
    const float* gw = (const float*)d_in[5];
    const float* gb = (const float*)d_in[6];
    const float* fw = (const float*)d_in[7];
    const float* fb = (const float*)d_in[8];
    float* out = (float*)d_out;

    const size_t MB = 1024 * 1024;
    _Float16* wh  = (_Float16*)d_ws;
    _Float16* uht = (_Float16*)((char*)d_ws + 4 * MB);
    float* sq     = (float*)((char*)d_ws + 4 * MB + 65536);
    float* pot    = (float*)((char*)d_ws + 6 * MB + 65536);
    float* mult   = (float*)((char*)d_ws + 6 * MB + 65536 + 131072);
    _Float16* xh  = (_Float16*)((char*)d_ws + 8 * MB);
    const bool big = ws_size >= 72 * MB;

    hipLaunchKernelGGL(k0_convert, dim3(1024), dim3(256), 0, stream, gw, fw, U, wh, uht);
    if (big) hipLaunchKernelGGL(k0_x<true>,  dim3(256), dim3(256), 0, stream, x, Vw, xh, pot);
    else     hipLaunchKernelGGL(k0_x<false>, dim3(256), dim3(256), 0, stream, x, Vw, xh, pot);
    hipLaunchKernelGGL(k1_v, dim3(512), dim3(256), 0, stream, v, uht, pot, sq, mult);
    if (big) hipLaunchKernelGGL(k2_main<true>,  dim3(4096), dim3(256), 0, stream,
                                x, v, wh, xh, W, gb, fb, sq, pot, mult, out);
    else     hipLaunchKernelGGL(k2_main<false>, dim3(4096), dim3(256), 0, stream,
                                x, v, wh, xh, W, gb, fb, sq, pot, mult, out);
}